// Round 2
// baseline (99.791 us; speedup 1.0000x reference)
//
#include <hip/hip_runtime.h>
#include <math.h>

#define NN 256
#define LL 4096
#define DL 64
#define DC 128
#define KS 15
#define NJ 60                 // 4 token values * 15 taps
#define LOUT (LL - KS + 1)    // 4082
#define RSQRT_DC 0.08838834764831843f
#define INV_LOUT (1.0f / (float)LOUT)

// Sequence-independent tables (computed by prep_kernel):
//   g_P[j][d]   = (Wq · ctb[j])[d]        60x128
//   g_Kc[j][d]  = (Wk · ctb[j])[d]        60x128
//   g_vtb[j][d] = (Wv · ctb[j])[d]        60x128
//   g_y[d]   = (Wq·conv_b + bq)[d]
//   g_t[d]   = (Wk·conv_b + bk)[d]
//   g_wvb[d] = (Wv·conv_b + bv)[d]
// where ctb[j] (j = v*15+k) is the conv contribution of token value v at tap k.
__device__ __align__(16) float g_P[NJ * DC];
__device__ __align__(16) float g_Kc[NJ * DC];
__device__ __align__(16) float g_vtb[NJ * DC];
__device__ __align__(16) float g_y[DC];
__device__ __align__(16) float g_t[DC];
__device__ __align__(16) float g_wvb[DC];

// ---------------- K1: build tables. blocks 0..59: row j; block 60: bias row ----------------
__global__ __launch_bounds__(512) void prep_kernel(const float* __restrict__ emb,
                                                   const float* __restrict__ conv_w,
                                                   const float* __restrict__ conv_b,
                                                   const float* __restrict__ Wq, const float* __restrict__ bq,
                                                   const float* __restrict__ Wk, const float* __restrict__ bk,
                                                   const float* __restrict__ Wv, const float* __restrict__ bv) {
    const int b = blockIdx.x, tid = threadIdx.x;
    __shared__ __align__(16) float xL[DC];   // ctb row j, or conv_b for block 60
    __shared__ float embL[DL];

    if (b < NJ) {
        const int v = b / KS, k = b % KS;
        if (tid < DL) embL[tid] = emb[v * DL + tid];
        __syncthreads();
        // ctb[j][c] = sum_i emb[v][i] * conv_w[c][i][k]; 4 threads per channel c
        {
            const int c = tid >> 2, s = tid & 3;
            float p = 0.f;
#pragma unroll
            for (int ii = 0; ii < 16; ++ii) {
                const int i = s * 16 + ii;
                p += embL[i] * conv_w[(size_t)(c * DL + i) * KS + k];
            }
            p += __shfl_down(p, 2, 4);
            p += __shfl_down(p, 1, 4);
            if (s == 0) xL[c] = p;
        }
        __syncthreads();
    } else {
        if (tid < DC) xL[tid] = conv_b[tid];
        __syncthreads();
    }

    // three 128x128 matvecs of xL: 4 threads per output row d
    const int d = tid >> 2, s = tid & 3;
    const float4* x4 = (const float4*)xL;
    const float4* wq = (const float4*)(Wq + (size_t)d * DC) + s * 8;
    const float4* wk = (const float4*)(Wk + (size_t)d * DC) + s * 8;
    const float4* wv = (const float4*)(Wv + (size_t)d * DC) + s * 8;
    float pq = 0.f, pk = 0.f, pv = 0.f;
#pragma unroll
    for (int j = 0; j < 8; ++j) {
        const float4 xv = x4[s * 8 + j];
        const float4 aq = wq[j];
        pq += aq.x * xv.x + aq.y * xv.y + aq.z * xv.z + aq.w * xv.w;
        const float4 ak = wk[j];
        pk += ak.x * xv.x + ak.y * xv.y + ak.z * xv.z + ak.w * xv.w;
        const float4 av = wv[j];
        pv += av.x * xv.x + av.y * xv.y + av.z * xv.z + av.w * xv.w;
    }
    pq += __shfl_down(pq, 2, 4); pq += __shfl_down(pq, 1, 4);
    pk += __shfl_down(pk, 2, 4); pk += __shfl_down(pk, 1, 4);
    pv += __shfl_down(pv, 2, 4); pv += __shfl_down(pv, 1, 4);
    if (s == 0) {
        if (b < NJ) {
            g_P[b * DC + d]   = pq;
            g_Kc[b * DC + d]  = pk;
            g_vtb[b * DC + d] = pv;
        } else {
            g_y[d]   = pq + bq[d];
            g_t[d]   = pk + bk[d];
            g_wvb[d] = pv + bv[d];
        }
    }
}

template <int NW>
__device__ __forceinline__ float bsum(float v, float* red, int tid) {
#pragma unroll
    for (int off = 32; off > 0; off >>= 1) v += __shfl_down(v, off, 64);
    if ((tid & 63) == 0) red[tid >> 6] = v;
    __syncthreads();
    float r = 0.f;
#pragma unroll
    for (int w = 0; w < NW; ++w) r += red[w];
    __syncthreads();
    return r;
}

template <int NW>
__device__ __forceinline__ float bmax(float v, float* red, int tid) {
#pragma unroll
    for (int off = 32; off > 0; off >>= 1) v = fmaxf(v, __shfl_down(v, off, 64));
    if ((tid & 63) == 0) red[tid >> 6] = v;
    __syncthreads();
    float r = red[0];
#pragma unroll
    for (int w = 1; w < NW; ++w) r = fmaxf(r, red[w]);
    __syncthreads();
    return r;
}

// ---------------- K2: per-sequence, everything wide-parallel ----------------
__global__ __launch_bounds__(512) void encode_kernel(const int* __restrict__ tokens,
                                                     float* __restrict__ out) {
    const int n = blockIdx.x, tid = threadIdx.x;

    __shared__ unsigned tok2L[258];
    __shared__ float stabL[64];
    __shared__ float cfL[NJ];
    __shared__ __align__(16) float qL[DC];
    __shared__ float yL[DC], tL[DC];
    __shared__ float qpart[4][DC];
    __shared__ float Tt[1024];
    __shared__ float AccL[45];
    __shared__ float red[8];
    __shared__ int totw[8][4];

    // ---- Phase A: pack tokens + per-dword counts; stage y,t; zero Acc ----
    int c0 = 0, c1 = 0, c2 = 0, c3 = 0;
    if (tid < 256) {
        const int4* tv = (const int4*)(tokens + (size_t)n * LL) + tid * 4;
        unsigned w = 0;
#pragma unroll
        for (int m = 0; m < 4; ++m) {
            int4 t4 = tv[m];
            w |= ((unsigned)t4.x | ((unsigned)t4.y << 2) |
                  ((unsigned)t4.z << 4) | ((unsigned)t4.w << 6)) << (8 * m);
        }
        tok2L[tid] = w;
        unsigned y, z;
        y = w;               z = (y | (y >> 1)) & 0x55555555u; c0 = 16 - __popc(z);
        y = w ^ 0x55555555u; z = (y | (y >> 1)) & 0x55555555u; c1 = 16 - __popc(z);
        y = w ^ 0xAAAAAAAAu; z = (y | (y >> 1)) & 0x55555555u; c2 = 16 - __popc(z);
        y = w ^ 0xFFFFFFFFu; z = (y | (y >> 1)) & 0x55555555u; c3 = 16 - __popc(z);
    } else {
        const int i = tid - 256;
        if (i < DC) yL[i] = g_y[i];
        else tL[i - DC] = g_t[i - DC];
        if (i < 45) AccL[i] = 0.f;
        if (i == 45) { tok2L[256] = 0u; tok2L[257] = 0u; }
    }
#pragma unroll
    for (int off = 32; off > 0; off >>= 1) {
        c0 += __shfl_down(c0, off, 64); c1 += __shfl_down(c1, off, 64);
        c2 += __shfl_down(c2, off, 64); c3 += __shfl_down(c3, off, 64);
    }
    if ((tid & 63) == 0) {
        const int wv = tid >> 6;
        totw[wv][0] = c0; totw[wv][1] = c1; totw[wv][2] = c2; totw[wv][3] = c3;
    }
    __syncthreads();

    // ---- Phase B: cf[v*15+k] = #tokens==v in window [k, k+LOUT) ----
    if (tid < KS) {
        const int k = tid;
        int tot4[4];
#pragma unroll
        for (int v = 0; v < 4; ++v) {
            int t = 0;
#pragma unroll
            for (int w = 0; w < 8; ++w) t += totw[w][v];
            tot4[v] = t;
        }
        const unsigned dwF = tok2L[0];
        const unsigned dwL = tok2L[255];
        const unsigned pm = (k == 0) ? 0u : ((1u << (2 * k)) - 1u);
        const unsigned sm = (k == 14) ? 0u : (0xFFFFFFFFu << (2 * (k + 2)));
#pragma unroll
        for (int v = 0; v < 4; ++v) {
            const unsigned patt = (unsigned)v * 0x55555555u;
            unsigned yf = dwF ^ patt, zf = (yf | (yf >> 1)) & 0x55555555u;
            unsigned yl = dwL ^ patt, zl = (yl | (yl >> 1)) & 0x55555555u;
            const int pre = k - __popc(zf & pm);
            const int suf = (14 - k) - __popc(zl & sm);
            cfL[v * KS + k] = (float)(tot4[v] - pre - suf);
        }
    }
    __syncthreads();

    // ---- Phase C: q = y + INV_LOUT * sum_i cf[i] * P[i]  (coalesced over channels) ----
    {
        const int cs = tid >> 7;       // 0..3 : which 15-row chunk
        const int cc = tid & 127;      // channel
        float pq = 0.f;
#pragma unroll
        for (int ii = 0; ii < 15; ++ii) {
            const int i = cs * 15 + ii;
            pq += cfL[i] * g_P[i * DC + cc];
        }
        qpart[cs][cc] = pq;
    }
    __syncthreads();
    if (tid < DC)
        qL[tid] = yL[tid] + INV_LOUT * (qpart[0][tid] + qpart[1][tid] + qpart[2][tid] + qpart[3][tid]);
    __syncthreads();

    // ---- Phase D: stab[j] = q . Kc[j] / sqrt(DC); base = q . t / sqrt(DC) ----
    if (tid < 480) {
        const int j = tid >> 3, s = tid & 7;
        const float4* kc = (const float4*)(g_Kc + (size_t)j * DC) + s * 4;
        const float4* q4 = (const float4*)qL + s * 4;
        float sd = 0.f;
#pragma unroll
        for (int u = 0; u < 4; ++u) {
            const float4 a = kc[u], q = q4[u];
            sd += a.x * q.x + a.y * q.y + a.z * q.z + a.w * q.w;
        }
        sd += __shfl_down(sd, 4, 8);
        sd += __shfl_down(sd, 2, 8);
        sd += __shfl_down(sd, 1, 8);
        if (s == 0) stabL[j] = sd * RSQRT_DC;
    } else {
        const int s2 = tid - 480;      // 0..31 (lanes 32..63 of wave 7)
        float sd = 0.f;
#pragma unroll
        for (int u = 0; u < 4; ++u) {
            const int c = s2 * 4 + u;
            sd += tL[c] * qL[c];
        }
#pragma unroll
        for (int off = 16; off > 0; off >>= 1) sd += __shfl_down(sd, off, 32);
        if (s2 == 0) stabL[60] = sd * RSQRT_DC;
    }
    __syncthreads();

    // ---- Phase E: chunk tables Tt[j*256+b] ----
    const float base = stabL[60];
    for (int e = tid; e < 1024; e += 512) {
        const int j = e >> 8, bb = e & 255;
        float s = stabL[(bb & 3) * KS + 4 * j] +
                  stabL[((bb >> 2) & 3) * KS + 4 * j + 1] +
                  stabL[((bb >> 4) & 3) * KS + 4 * j + 2];
        if (j < 3) s += stabL[((bb >> 6) & 3) * KS + 4 * j + 3];
        Tt[e] = s;
    }
    __syncthreads();

    // ---- Phase F: scores, softmax, attn-weighted histogram ----
    const unsigned d0 = tok2L[tid >> 1], d1 = tok2L[(tid >> 1) + 1];
    const unsigned long long W = (unsigned long long)d0 | ((unsigned long long)d1 << 32);
    const int sbase = (tid & 1) << 4;
    const int t0 = tid * 8;
    float sc[8];
    float lmax = -3.4e38f;
#pragma unroll
    for (int p = 0; p < 8; ++p) {
        const unsigned w = (unsigned)(W >> (sbase + 2 * p));
        const float s = base + Tt[w & 255] + Tt[256 + ((w >> 8) & 255)] +
                        Tt[512 + ((w >> 16) & 255)] + Tt[768 + ((w >> 24) & 63)];
        sc[p] = (t0 + p < LOUT) ? s : -3.4e38f;
        lmax = fmaxf(lmax, sc[p]);
    }
    const float m = bmax<8>(lmax, red, tid);
    float lsum = 0.f;
#pragma unroll
    for (int p = 0; p < 8; ++p) {
        const float e = (t0 + p < LOUT) ? __expf(sc[p] - m) : 0.f;
        sc[p] = e; lsum += e;
    }
    const float S = bsum<8>(lsum, red, tid);
    const float invS = 1.0f / S;

    float a1[KS], a2[KS], a3[KS];
#pragma unroll
    for (int k = 0; k < KS; ++k) { a1[k] = 0.f; a2[k] = 0.f; a3[k] = 0.f; }
#pragma unroll
    for (int p = 0; p < 8; ++p) {
        const float e = sc[p];
        const unsigned w = (unsigned)(W >> (sbase + 2 * p));
#pragma unroll
        for (int k = 0; k < KS; ++k) {
            const int v = (int)((w >> (2 * k)) & 3u);
            a1[k] += (v == 1) ? e : 0.f;
            a2[k] += (v == 2) ? e : 0.f;
            a3[k] += (v == 3) ? e : 0.f;
        }
    }
    {
        const int lane = tid & 63;
#pragma unroll
        for (int k = 0; k < KS; ++k) {
            float v1 = a1[k], v2 = a2[k], v3 = a3[k];
#pragma unroll
            for (int off = 32; off > 0; off >>= 1) {
                v1 += __shfl_down(v1, off, 64);
                v2 += __shfl_down(v2, off, 64);
                v3 += __shfl_down(v3, off, 64);
            }
            if (lane == 0) {
                atomicAdd(&AccL[k], v1);
                atomicAdd(&AccL[KS + k], v2);
                atomicAdd(&AccL[2 * KS + k], v3);
            }
        }
    }
    __syncthreads();

    // ---- Phase G: out = wvb + invS * sum_j AccFull[j] * vtb[j]  (v=0 from S) ----
    if (tid < DC) {
        float sacc = 0.f;
#pragma unroll
        for (int k = 0; k < KS; ++k) {
            const float a0 = S - AccL[k] - AccL[KS + k] - AccL[2 * KS + k];
            sacc += a0 * g_vtb[k * DC + tid];
        }
#pragma unroll
        for (int j = KS; j < NJ; ++j) sacc += AccL[j - KS] * g_vtb[j * DC + tid];
        out[(size_t)n * DC + tid] = g_wvb[tid] + sacc * invS;
    }
}

extern "C" void kernel_launch(void* const* d_in, const int* in_sizes, int n_in,
                              void* d_out, int out_size, void* d_ws, size_t ws_size,
                              hipStream_t stream) {
    const int*   tokens = (const int*)d_in[0];
    const float* emb    = (const float*)d_in[1];
    const float* conv_w = (const float*)d_in[2];
    const float* conv_b = (const float*)d_in[3];
    const float* Wq     = (const float*)d_in[4];
    const float* bq     = (const float*)d_in[5];
    const float* Wk     = (const float*)d_in[6];
    const float* bk     = (const float*)d_in[7];
    const float* Wv     = (const float*)d_in[8];
    const float* bv     = (const float*)d_in[9];
    float* out = (float*)d_out;
    (void)d_ws; (void)ws_size;   // workspace intentionally unused

    prep_kernel<<<NJ + 1, 512, 0, stream>>>(emb, conv_w, conv_b, Wq, bq, Wk, bk, Wv, bv);
    encode_kernel<<<NN, 512, 0, stream>>>(tokens, out);
}